// Round 10
// baseline (590.945 us; speedup 1.0000x reference)
//
#include <hip/hip_runtime.h>
#include <hip/hip_cooperative_groups.h>

namespace cg = cooperative_groups;

#define NNODES 4096
#define CAP 256

// Single fused cooperative kernel. Phases separated by grid.sync():
//  P0: edge extraction (4096 rows) interleaved with gemm0+scores0 (1024 tiles)
//  P1: attn layer 0 (H=8), sparse softmax + float4 gather
//  P2: gemm1 as 16-row tiles x 16-way split-K (4096 items -> full machine)
//  P3: reduce 16 partials + bias + scores1
//  P4: attn layer 1 (H=1): raw scores -> [barrier] wave0-only softmax ->
//      [barrier] 16-way gather.  (R9 lesson: multi-wave redundant in-place
//      exp overwrite races across waves — single-wave ownership only.)
// All phases are grid-stride -> correct for any granted grid size.
__global__ __launch_bounds__(256, 8) void fused_gat(
    const float* __restrict__ mask, const float* __restrict__ x,
    const float* __restrict__ W0, const float* __restrict__ b0,
    const float* __restrict__ a_src0, const float* __restrict__ a_tgt0,
    const float* __restrict__ W1, const float* __restrict__ b1,
    const float* __restrict__ a_src1, const float* __restrict__ a_tgt1,
    float* __restrict__ out, float* __restrict__ proj0, float* __restrict__ h0,
    float* __restrict__ proj1, float* __restrict__ ssrc0,
    float* __restrict__ stgt0, float* __restrict__ ssrc1,
    float* __restrict__ stgt1, int* __restrict__ deg, int* __restrict__ cols,
    float* __restrict__ part) {
  cg::grid_group grid = cg::this_grid();
  __shared__ float smem[3200];  // 12.8 KB union for all phases
  const int t = threadIdx.x;
  const int G = gridDim.x;
  const int lane = t & 63, wid = t >> 6;

  // ------------------- P0: edges (items<4096) + gemm0 (items>=4096) ----------
  for (int item = blockIdx.x; item < NNODES + 1024; item += G) {
    if (item < NNODES) {
      const int n = item;
      int* wsum = (int*)smem;
      const float4* row = (const float4*)(mask + (size_t)n * NNODES);
      float4 v[4];
      int cnt = 0;
#pragma unroll
      for (int j = 0; j < 4; ++j) {
        v[j] = row[t + 256 * j];  // coalesced
        cnt += (v[j].x == 0.0f) + (v[j].y == 0.0f) + (v[j].z == 0.0f) +
               (v[j].w == 0.0f);
      }
      int xs = cnt;
#pragma unroll
      for (int o = 1; o < 64; o <<= 1) {
        int y = __shfl_up(xs, o);
        if (lane >= o) xs += y;
      }
      if (lane == 63) wsum[wid] = xs;
      __syncthreads();
      int base = 0;
      for (int w = 0; w < wid; ++w) base += wsum[w];
      int off = base + xs - cnt;
      if (t == 0) {
        int total = wsum[0] + wsum[1] + wsum[2] + wsum[3];
        deg[n] = total < CAP ? total : CAP;
      }
      int* dst = cols + (size_t)n * CAP;
#pragma unroll
      for (int j = 0; j < 4; ++j) {
        const int c0 = (t + 256 * j) * 4;
        float fv[4] = {v[j].x, v[j].y, v[j].z, v[j].w};
#pragma unroll
        for (int k = 0; k < 4; ++k) {
          if (fv[k] == 0.0f) {
            if (off < CAP) dst[off] = c0 + k;
            ++off;
          }
        }
      }
    } else {
      // gemm0: 32x64 tile, K=128, BK=32 chunks, 2x4 reg blocking (R3 lesson:
      // bounded unroll, no spill) + fused scores0 epilogue
      float(*As)[36] = (float(*)[36])smem;
      float(*Ws)[64] = (float(*)[64])(smem + 32 * 36);
      const int bx = item - NNODES;
      const int brow = (bx & 127) * 32;
      const int head = bx >> 7;
      const int bcol = head * 64;
      const int tx = t & 15, ty = t >> 4;
      const int ar = t >> 3, ak = (t & 7) * 4;
      float acc[2][4] = {};
      for (int c = 0; c < 4; ++c) {
        const int k0 = c * 32;
        *(float4*)&As[ar][ak] =
            *(const float4*)&x[(size_t)(brow + ar) * 128 + k0 + ak];
#pragma unroll
        for (int q = 0; q < 2; ++q) {
          int i = t + q * 256;
          int k = i >> 4, c4 = (i & 15) * 4;
          *(float4*)&Ws[k][c4] =
              *(const float4*)&W0[(size_t)(k0 + k) * 512 + bcol + c4];
        }
        __syncthreads();
#pragma unroll 2
        for (int kk = 0; kk < 32; kk += 4) {
          float4 a0 = *(const float4*)&As[ty * 2 + 0][kk];
          float4 a1 = *(const float4*)&As[ty * 2 + 1][kk];
#pragma unroll
          for (int j = 0; j < 4; ++j) {
            float4 w = *(const float4*)&Ws[kk + j][tx * 4];
            float av0 = ((const float*)&a0)[j];
            float av1 = ((const float*)&a1)[j];
            acc[0][0] = fmaf(av0, w.x, acc[0][0]);
            acc[0][1] = fmaf(av0, w.y, acc[0][1]);
            acc[0][2] = fmaf(av0, w.z, acc[0][2]);
            acc[0][3] = fmaf(av0, w.w, acc[0][3]);
            acc[1][0] = fmaf(av1, w.x, acc[1][0]);
            acc[1][1] = fmaf(av1, w.y, acc[1][1]);
            acc[1][2] = fmaf(av1, w.z, acc[1][2]);
            acc[1][3] = fmaf(av1, w.w, acc[1][3]);
          }
        }
        __syncthreads();
      }
      const float4 bv = *(const float4*)&b0[bcol + tx * 4];
      const float4 as = *(const float4*)&a_src0[head * 64 + tx * 4];
      const float4 at = *(const float4*)&a_tgt0[head * 64 + tx * 4];
#pragma unroll
      for (int r = 0; r < 2; ++r) {
        float4 o;
        o.x = acc[r][0] + bv.x; o.y = acc[r][1] + bv.y;
        o.z = acc[r][2] + bv.z; o.w = acc[r][3] + bv.w;
        const size_t node = brow + ty * 2 + r;
        *(float4*)&proj0[node * 512 + bcol + tx * 4] = o;
        float ps = o.x * as.x + o.y * as.y + o.z * as.z + o.w * as.w;
        float pt = o.x * at.x + o.y * at.y + o.z * at.z + o.w * at.w;
#pragma unroll
        for (int m = 8; m; m >>= 1) {
          ps += __shfl_xor(ps, m);
          pt += __shfl_xor(pt, m);
        }
        if (tx == 0) {
          ssrc0[node * 8 + head] = ps;
          stgt0[node * 8 + head] = pt;
        }
      }
    }
    __syncthreads();  // smem reuse safety between items
  }
  grid.sync();

  // ------------------- P1: attn layer 0 (H=8) --------------------------------
  for (int n = blockIdx.x; n < NNODES; n += G) {
    int* sm_ = (int*)smem;            // [256]
    float* sw = smem + 256;           // [2048]
    float* sinv = smem + 2304;        // [8]
    float4* buf = (float4*)(smem + 2312);  // [128] (byte 9248, 16-aligned)
    const int d = deg[n];
    for (int i = t; i < d; i += 256) sm_[i] = cols[(size_t)n * CAP + i];
    __syncthreads();
    for (int i = t; i < d * 8; i += 256) {
      int e = i >> 3, h = i & 7;
      float s = ssrc0[n * 8 + h] + stgt0[sm_[e] * 8 + h];
      sw[i] = s >= 0.f ? s : 0.2f * s;
    }
    __syncthreads();
    for (int h = wid; h < 8; h += 4) {  // each wave owns its heads (no race)
      float mx = -1e30f;
      for (int e = lane; e < d; e += 64) mx = fmaxf(mx, sw[e * 8 + h]);
#pragma unroll
      for (int o = 32; o; o >>= 1) mx = fmaxf(mx, __shfl_xor(mx, o));
      float sum = 0.f;
      for (int e = lane; e < d; e += 64) {
        float w = __expf(sw[e * 8 + h] - mx);
        sw[e * 8 + h] = w;
        sum += w;
      }
#pragma unroll
      for (int o = 32; o; o >>= 1) sum += __shfl_xor(sum, o);
      if (lane == 0) sinv[h] = 1.0f / sum;
    }
    __syncthreads();
    const int f4 = t & 127, grp = t >> 7;
    const int h = f4 >> 4;
    float4 acc = make_float4(0.f, 0.f, 0.f, 0.f);
    for (int e = grp; e < d; e += 2) {
      const float w = sw[e * 8 + h];
      const float4 pv = *(const float4*)&proj0[(size_t)sm_[e] * 512 + f4 * 4];
      acc.x = fmaf(w, pv.x, acc.x);
      acc.y = fmaf(w, pv.y, acc.y);
      acc.z = fmaf(w, pv.z, acc.z);
      acc.w = fmaf(w, pv.w, acc.w);
    }
    if (grp == 1) buf[f4] = acc;
    __syncthreads();
    if (grp == 0) {
      const float4 o2 = buf[f4];
      const float s = sinv[h];
      float4 o;
      o.x = (acc.x + o2.x) * s;
      o.y = (acc.y + o2.y) * s;
      o.z = (acc.z + o2.z) * s;
      o.w = (acc.w + o2.w) * s;
      *(float4*)&h0[(size_t)n * 512 + f4 * 4] = o;
    }
    __syncthreads();  // smem reuse before next node
  }
  grid.sync();

  // ------------------- P2: gemm1, 16-row tiles x 16 split-K (KC=32) ----------
  for (int item = blockIdx.x; item < 4096; item += G) {
    float(*As)[36] = (float(*)[36])smem;              // 16 x 36
    float(*Ws)[64] = (float(*)[64])(smem + 16 * 36);  // 32 x 64
    const int rowtile = item & 255;
    const int z = item >> 8;
    const int k0 = z * 32;
    const int tx = t & 15, ty = t >> 4;
    if (t < 128) {
      int r = t >> 3, k4 = (t & 7) * 4;
      *(float4*)&As[r][k4] =
          *(const float4*)&h0[(size_t)(rowtile * 16 + r) * 512 + k0 + k4];
    }
#pragma unroll
    for (int q = 0; q < 2; ++q) {
      int i = t + q * 256;
      int k = i >> 4, c4 = (i & 15) * 4;
      *(float4*)&Ws[k][c4] = *(const float4*)&W1[(size_t)(k0 + k) * 64 + c4];
    }
    __syncthreads();
    float acc[4] = {};
#pragma unroll 2
    for (int kk = 0; kk < 32; kk += 4) {
      float4 a4 = *(const float4*)&As[ty][kk];
#pragma unroll
      for (int j = 0; j < 4; ++j) {
        float4 w = *(const float4*)&Ws[kk + j][tx * 4];
        float av = ((const float*)&a4)[j];
        acc[0] = fmaf(av, w.x, acc[0]);
        acc[1] = fmaf(av, w.y, acc[1]);
        acc[2] = fmaf(av, w.z, acc[2]);
        acc[3] = fmaf(av, w.w, acc[3]);
      }
    }
    __syncthreads();  // before smem reuse next item
    float4 o = make_float4(acc[0], acc[1], acc[2], acc[3]);
    *(float4*)&part[(size_t)z * 262144 + (size_t)(rowtile * 16 + ty) * 64 +
                    tx * 4] = o;
  }
  grid.sync();

  // ------------------- P3: reduce 16 partials + bias + scores1 ---------------
  for (int i = blockIdx.x * 256 + t; i < 65536; i += G * 256) {
    const float4* p4 = (const float4*)part;
    float4 r = p4[i];
#pragma unroll
    for (int p = 1; p < 16; ++p) {
      float4 v = p4[i + p * 65536];
      r.x += v.x; r.y += v.y; r.z += v.z; r.w += v.w;
    }
    const int f4 = i & 15;
    const float4 bb = *(const float4*)&b1[f4 * 4];
    r.x += bb.x; r.y += bb.y; r.z += bb.z; r.w += bb.w;
    ((float4*)proj1)[i] = r;
    const float4 as = *(const float4*)&a_src1[f4 * 4];
    const float4 at = *(const float4*)&a_tgt1[f4 * 4];
    float ps = r.x * as.x + r.y * as.y + r.z * as.z + r.w * as.w;
    float pt = r.x * at.x + r.y * at.y + r.z * at.z + r.w * at.w;
#pragma unroll
    for (int m = 8; m; m >>= 1) {
      ps += __shfl_xor(ps, m);
      pt += __shfl_xor(pt, m);
    }
    if (f4 == 0) {
      const int node = i >> 4;
      ssrc1[node] = ps;
      stgt1[node] = pt;
    }
  }
  grid.sync();

  // ------------------- P4: attn layer 1 (H=1), 16-way edge split -------------
  for (int n = blockIdx.x; n < NNODES; n += G) {
    int* sm_ = (int*)smem;                // [0,256)
    float* sw = smem + 256;               // [256,512)
    float4* buf = (float4*)(smem + 512);  // [512,1536) = 256 float4
    float* s_sinv = smem + 1536;          // [1536]
    const int d = deg[n];
    for (int i = t; i < d; i += 256) sm_[i] = cols[(size_t)n * CAP + i];
    __syncthreads();
    const float ssn = ssrc1[n];
    for (int i = t; i < d; i += 256) {
      float s = ssn + stgt1[sm_[i]];
      sw[i] = s >= 0.f ? s : 0.2f * s;
    }
    __syncthreads();
    // wave 0 ONLY: max + exp-overwrite + sum (single-wave ownership, no race)
    if (wid == 0) {
      float mx = -1e30f;
      for (int e = lane; e < d; e += 64) mx = fmaxf(mx, sw[e]);
#pragma unroll
      for (int o = 32; o; o >>= 1) mx = fmaxf(mx, __shfl_xor(mx, o));
      float sum = 0.f;
      for (int e = lane; e < d; e += 64) {
        float w = __expf(sw[e] - mx);
        sw[e] = w;
        sum += w;
      }
#pragma unroll
      for (int o = 32; o; o >>= 1) sum += __shfl_xor(sum, o);
      if (lane == 0) s_sinv[0] = 1.0f / sum;
    }
    __syncthreads();
    const float sinv = s_sinv[0];
    const int f4 = t & 15, grp = t >> 4;  // 16 outputs x 16-way edges
    float4 acc = make_float4(0.f, 0.f, 0.f, 0.f);
    for (int e = grp; e < d; e += 16) {
      const float w = sw[e];
      const float4 pv = *(const float4*)&proj1[(size_t)sm_[e] * 64 + f4 * 4];
      acc.x = fmaf(w, pv.x, acc.x);
      acc.y = fmaf(w, pv.y, acc.y);
      acc.z = fmaf(w, pv.z, acc.z);
      acc.w = fmaf(w, pv.w, acc.w);
    }
    if (grp > 0) buf[grp * 16 + f4] = acc;
    __syncthreads();
    if (grp == 0) {
#pragma unroll
      for (int p = 1; p < 16; ++p) {
        float4 v = buf[p * 16 + f4];
        acc.x += v.x; acc.y += v.y; acc.z += v.z; acc.w += v.w;
      }
      acc.x *= sinv; acc.y *= sinv; acc.z *= sinv; acc.w *= sinv;
      *(float4*)&out[(size_t)n * 64 + f4 * 4] = acc;
    }
    __syncthreads();  // smem reuse before next node
  }
}

// ---------------------------------------------------------------------------
extern "C" void kernel_launch(void* const* d_in, const int* in_sizes, int n_in,
                              void* d_out, int out_size, void* d_ws, size_t ws_size,
                              hipStream_t stream) {
  const float* x      = (const float*)d_in[0];
  const float* mask   = (const float*)d_in[1];
  const float* W0     = (const float*)d_in[2];
  const float* b0     = (const float*)d_in[3];
  const float* a_src0 = (const float*)d_in[4];
  const float* a_tgt0 = (const float*)d_in[5];
  const float* W1     = (const float*)d_in[6];
  const float* b1     = (const float*)d_in[7];
  const float* a_src1 = (const float*)d_in[8];
  const float* a_tgt1 = (const float*)d_in[9];
  float* out = (float*)d_out;

  // workspace layout (~37.3 MB of the ws)
  float* ws    = (float*)d_ws;
  float* proj0 = ws;                          // 4096*512
  float* h0    = proj0 + NNODES * 512;        // 4096*512
  float* proj1 = h0 + NNODES * 512;           // 4096*64
  float* ssrc0 = proj1 + NNODES * 64;         // 4096*8
  float* stgt0 = ssrc0 + NNODES * 8;          // 4096*8
  float* ssrc1 = stgt0 + NNODES * 8;          // 4096
  float* stgt1 = ssrc1 + NNODES;              // 4096
  int* deg  = (int*)(stgt1 + NNODES);         // 4096
  int* cols = deg + NNODES;                   // 4096*CAP
  float* part = (float*)(cols + NNODES * CAP);  // 16*4096*64 split-K partials

  int occ = 0;
  hipOccupancyMaxActiveBlocksPerMultiprocessor(&occ, (const void*)fused_gat,
                                               256, 0);
  if (occ < 1) occ = 4;
  int grid = occ * 256;  // 256 CUs
  if (grid > 2048) grid = 2048;

  void* args[] = {&mask, &x, &W0, &b0, &a_src0, &a_tgt0, &W1, &b1,
                  &a_src1, &a_tgt1, &out, &proj0, &h0, &proj1, &ssrc0,
                  &stgt0, &ssrc1, &stgt1, &deg, &cols, &part};
  hipLaunchCooperativeKernel((const void*)fused_gat, dim3(grid), dim3(256),
                             args, 0, stream);
}

// Round 11
// 382.489 us; speedup vs baseline: 1.5450x; 1.5450x over previous
//
#include <hip/hip_runtime.h>
#include <hip/hip_cooperative_groups.h>

namespace cg = cooperative_groups;

#define NNODES 4096
#define CAP 256

// Single fused cooperative kernel. Phases separated by grid.sync():
//  P0: edge extraction (4096 rows) interleaved with gemm0+scores0 (1024 tiles)
//  P1: attn layer 0 (H=8), sparse softmax + float4 gather
//  P2: gemm1 as 16-row tiles x 16-way split-K (4096 items -> full machine)
//  P3: reduce 16 partials + bias + scores1
//  P4: attn layer 1 (H=1): wave0-only softmax (R9 lesson: single-wave
//      ownership of in-place exp).
// R10 lesson: do NOT force min-waves via __launch_bounds__ — (256,8) forced
// 32 VGPR -> spills everywhere -> 8x regression. Let the compiler pick VGPR;
// grid is sized from the real occupancy query, so cooperative co-residency
// still holds.
__global__ __launch_bounds__(256) void fused_gat(
    const float* __restrict__ mask, const float* __restrict__ x,
    const float* __restrict__ W0, const float* __restrict__ b0,
    const float* __restrict__ a_src0, const float* __restrict__ a_tgt0,
    const float* __restrict__ W1, const float* __restrict__ b1,
    const float* __restrict__ a_src1, const float* __restrict__ a_tgt1,
    float* __restrict__ out, float* __restrict__ proj0, float* __restrict__ h0,
    float* __restrict__ proj1, float* __restrict__ ssrc0,
    float* __restrict__ stgt0, float* __restrict__ ssrc1,
    float* __restrict__ stgt1, int* __restrict__ deg, int* __restrict__ cols,
    float* __restrict__ part) {
  cg::grid_group grid = cg::this_grid();
  __shared__ float smem[3200];  // 12.8 KB union for all phases
  const int t = threadIdx.x;
  const int G = gridDim.x;
  const int lane = t & 63, wid = t >> 6;

  // ------------------- P0: edges (items<4096) + gemm0 (items>=4096) ----------
  for (int item = blockIdx.x; item < NNODES + 1024; item += G) {
    if (item < NNODES) {
      const int n = item;
      int* wsum = (int*)smem;
      const float4* row = (const float4*)(mask + (size_t)n * NNODES);
      float4 v[4];
      int cnt = 0;
#pragma unroll
      for (int j = 0; j < 4; ++j) {
        v[j] = row[t + 256 * j];  // coalesced
        cnt += (v[j].x == 0.0f) + (v[j].y == 0.0f) + (v[j].z == 0.0f) +
               (v[j].w == 0.0f);
      }
      int xs = cnt;
#pragma unroll
      for (int o = 1; o < 64; o <<= 1) {
        int y = __shfl_up(xs, o);
        if (lane >= o) xs += y;
      }
      if (lane == 63) wsum[wid] = xs;
      __syncthreads();
      int base = 0;
      for (int w = 0; w < wid; ++w) base += wsum[w];
      int off = base + xs - cnt;
      if (t == 0) {
        int total = wsum[0] + wsum[1] + wsum[2] + wsum[3];
        deg[n] = total < CAP ? total : CAP;
      }
      int* dst = cols + (size_t)n * CAP;
#pragma unroll
      for (int j = 0; j < 4; ++j) {
        const int c0 = (t + 256 * j) * 4;
        float fv[4] = {v[j].x, v[j].y, v[j].z, v[j].w};
#pragma unroll
        for (int k = 0; k < 4; ++k) {
          if (fv[k] == 0.0f) {
            if (off < CAP) dst[off] = c0 + k;
            ++off;
          }
        }
      }
    } else {
      // gemm0: 32x64 tile, K=128, BK=32 chunks, 2x4 reg blocking (R3 lesson:
      // bounded unroll, no spill) + fused scores0 epilogue
      float(*As)[36] = (float(*)[36])smem;
      float(*Ws)[64] = (float(*)[64])(smem + 32 * 36);
      const int bx = item - NNODES;
      const int brow = (bx & 127) * 32;
      const int head = bx >> 7;
      const int bcol = head * 64;
      const int tx = t & 15, ty = t >> 4;
      const int ar = t >> 3, ak = (t & 7) * 4;
      float acc[2][4] = {};
      for (int c = 0; c < 4; ++c) {
        const int k0 = c * 32;
        *(float4*)&As[ar][ak] =
            *(const float4*)&x[(size_t)(brow + ar) * 128 + k0 + ak];
#pragma unroll
        for (int q = 0; q < 2; ++q) {
          int i = t + q * 256;
          int k = i >> 4, c4 = (i & 15) * 4;
          *(float4*)&Ws[k][c4] =
              *(const float4*)&W0[(size_t)(k0 + k) * 512 + bcol + c4];
        }
        __syncthreads();
#pragma unroll 2
        for (int kk = 0; kk < 32; kk += 4) {
          float4 a0 = *(const float4*)&As[ty * 2 + 0][kk];
          float4 a1 = *(const float4*)&As[ty * 2 + 1][kk];
#pragma unroll
          for (int j = 0; j < 4; ++j) {
            float4 w = *(const float4*)&Ws[kk + j][tx * 4];
            float av0 = ((const float*)&a0)[j];
            float av1 = ((const float*)&a1)[j];
            acc[0][0] = fmaf(av0, w.x, acc[0][0]);
            acc[0][1] = fmaf(av0, w.y, acc[0][1]);
            acc[0][2] = fmaf(av0, w.z, acc[0][2]);
            acc[0][3] = fmaf(av0, w.w, acc[0][3]);
            acc[1][0] = fmaf(av1, w.x, acc[1][0]);
            acc[1][1] = fmaf(av1, w.y, acc[1][1]);
            acc[1][2] = fmaf(av1, w.z, acc[1][2]);
            acc[1][3] = fmaf(av1, w.w, acc[1][3]);
          }
        }
        __syncthreads();
      }
      const float4 bv = *(const float4*)&b0[bcol + tx * 4];
      const float4 as = *(const float4*)&a_src0[head * 64 + tx * 4];
      const float4 at = *(const float4*)&a_tgt0[head * 64 + tx * 4];
#pragma unroll
      for (int r = 0; r < 2; ++r) {
        float4 o;
        o.x = acc[r][0] + bv.x; o.y = acc[r][1] + bv.y;
        o.z = acc[r][2] + bv.z; o.w = acc[r][3] + bv.w;
        const size_t node = brow + ty * 2 + r;
        *(float4*)&proj0[node * 512 + bcol + tx * 4] = o;
        float ps = o.x * as.x + o.y * as.y + o.z * as.z + o.w * as.w;
        float pt = o.x * at.x + o.y * at.y + o.z * at.z + o.w * at.w;
#pragma unroll
        for (int m = 8; m; m >>= 1) {
          ps += __shfl_xor(ps, m);
          pt += __shfl_xor(pt, m);
        }
        if (tx == 0) {
          ssrc0[node * 8 + head] = ps;
          stgt0[node * 8 + head] = pt;
        }
      }
    }
    __syncthreads();  // smem reuse safety between items
  }
  grid.sync();

  // ------------------- P1: attn layer 0 (H=8) --------------------------------
  for (int n = blockIdx.x; n < NNODES; n += G) {
    int* sm_ = (int*)smem;            // [256]
    float* sw = smem + 256;           // [2048]
    float* sinv = smem + 2304;        // [8]
    float4* buf = (float4*)(smem + 2312);  // [128] (byte 9248, 16-aligned)
    const int d = deg[n];
    for (int i = t; i < d; i += 256) sm_[i] = cols[(size_t)n * CAP + i];
    __syncthreads();
    for (int i = t; i < d * 8; i += 256) {
      int e = i >> 3, h = i & 7;
      float s = ssrc0[n * 8 + h] + stgt0[sm_[e] * 8 + h];
      sw[i] = s >= 0.f ? s : 0.2f * s;
    }
    __syncthreads();
    for (int h = wid; h < 8; h += 4) {  // each wave owns its heads (no race)
      float mx = -1e30f;
      for (int e = lane; e < d; e += 64) mx = fmaxf(mx, sw[e * 8 + h]);
#pragma unroll
      for (int o = 32; o; o >>= 1) mx = fmaxf(mx, __shfl_xor(mx, o));
      float sum = 0.f;
      for (int e = lane; e < d; e += 64) {
        float w = __expf(sw[e * 8 + h] - mx);
        sw[e * 8 + h] = w;
        sum += w;
      }
#pragma unroll
      for (int o = 32; o; o >>= 1) sum += __shfl_xor(sum, o);
      if (lane == 0) sinv[h] = 1.0f / sum;
    }
    __syncthreads();
    const int f4 = t & 127, grp = t >> 7;
    const int h = f4 >> 4;
    float4 acc = make_float4(0.f, 0.f, 0.f, 0.f);
    for (int e = grp; e < d; e += 2) {
      const float w = sw[e * 8 + h];
      const float4 pv = *(const float4*)&proj0[(size_t)sm_[e] * 512 + f4 * 4];
      acc.x = fmaf(w, pv.x, acc.x);
      acc.y = fmaf(w, pv.y, acc.y);
      acc.z = fmaf(w, pv.z, acc.z);
      acc.w = fmaf(w, pv.w, acc.w);
    }
    if (grp == 1) buf[f4] = acc;
    __syncthreads();
    if (grp == 0) {
      const float4 o2 = buf[f4];
      const float s = sinv[h];
      float4 o;
      o.x = (acc.x + o2.x) * s;
      o.y = (acc.y + o2.y) * s;
      o.z = (acc.z + o2.z) * s;
      o.w = (acc.w + o2.w) * s;
      *(float4*)&h0[(size_t)n * 512 + f4 * 4] = o;
    }
    __syncthreads();  // smem reuse before next node
  }
  grid.sync();

  // ------------------- P2: gemm1, 16-row tiles x 16 split-K (KC=32) ----------
  for (int item = blockIdx.x; item < 4096; item += G) {
    float(*As)[36] = (float(*)[36])smem;              // 16 x 36
    float(*Ws)[64] = (float(*)[64])(smem + 16 * 36);  // 32 x 64
    const int rowtile = item & 255;
    const int z = item >> 8;
    const int k0 = z * 32;
    const int tx = t & 15, ty = t >> 4;
    if (t < 128) {
      int r = t >> 3, k4 = (t & 7) * 4;
      *(float4*)&As[r][k4] =
          *(const float4*)&h0[(size_t)(rowtile * 16 + r) * 512 + k0 + k4];
    }
#pragma unroll
    for (int q = 0; q < 2; ++q) {
      int i = t + q * 256;
      int k = i >> 4, c4 = (i & 15) * 4;
      *(float4*)&Ws[k][c4] = *(const float4*)&W1[(size_t)(k0 + k) * 64 + c4];
    }
    __syncthreads();
    float acc[4] = {};
#pragma unroll 2
    for (int kk = 0; kk < 32; kk += 4) {
      float4 a4 = *(const float4*)&As[ty][kk];
#pragma unroll
      for (int j = 0; j < 4; ++j) {
        float4 w = *(const float4*)&Ws[kk + j][tx * 4];
        float av = ((const float*)&a4)[j];
        acc[0] = fmaf(av, w.x, acc[0]);
        acc[1] = fmaf(av, w.y, acc[1]);
        acc[2] = fmaf(av, w.z, acc[2]);
        acc[3] = fmaf(av, w.w, acc[3]);
      }
    }
    __syncthreads();  // before smem reuse next item
    float4 o = make_float4(acc[0], acc[1], acc[2], acc[3]);
    *(float4*)&part[(size_t)z * 262144 + (size_t)(rowtile * 16 + ty) * 64 +
                    tx * 4] = o;
  }
  grid.sync();

  // ------------------- P3: reduce 16 partials + bias + scores1 ---------------
  for (int i = blockIdx.x * 256 + t; i < 65536; i += G * 256) {
    const float4* p4 = (const float4*)part;
    float4 r = p4[i];
#pragma unroll
    for (int p = 1; p < 16; ++p) {
      float4 v = p4[i + p * 65536];
      r.x += v.x; r.y += v.y; r.z += v.z; r.w += v.w;
    }
    const int f4 = i & 15;
    const float4 bb = *(const float4*)&b1[f4 * 4];
    r.x += bb.x; r.y += bb.y; r.z += bb.z; r.w += bb.w;
    ((float4*)proj1)[i] = r;
    const float4 as = *(const float4*)&a_src1[f4 * 4];
    const float4 at = *(const float4*)&a_tgt1[f4 * 4];
    float ps = r.x * as.x + r.y * as.y + r.z * as.z + r.w * as.w;
    float pt = r.x * at.x + r.y * at.y + r.z * at.z + r.w * at.w;
#pragma unroll
    for (int m = 8; m; m >>= 1) {
      ps += __shfl_xor(ps, m);
      pt += __shfl_xor(pt, m);
    }
    if (f4 == 0) {
      const int node = i >> 4;
      ssrc1[node] = ps;
      stgt1[node] = pt;
    }
  }
  grid.sync();

  // ------------------- P4: attn layer 1 (H=1), 16-way edge split -------------
  for (int n = blockIdx.x; n < NNODES; n += G) {
    int* sm_ = (int*)smem;                // [0,256)
    float* sw = smem + 256;               // [256,512)
    float4* buf = (float4*)(smem + 512);  // [512,1536) = 256 float4
    float* s_sinv = smem + 1536;          // [1536]
    const int d = deg[n];
    for (int i = t; i < d; i += 256) sm_[i] = cols[(size_t)n * CAP + i];
    __syncthreads();
    const float ssn = ssrc1[n];
    for (int i = t; i < d; i += 256) {
      float s = ssn + stgt1[sm_[i]];
      sw[i] = s >= 0.f ? s : 0.2f * s;
    }
    __syncthreads();
    // wave 0 ONLY: max + exp-overwrite + sum (single-wave ownership, no race)
    if (wid == 0) {
      float mx = -1e30f;
      for (int e = lane; e < d; e += 64) mx = fmaxf(mx, sw[e]);
#pragma unroll
      for (int o = 32; o; o >>= 1) mx = fmaxf(mx, __shfl_xor(mx, o));
      float sum = 0.f;
      for (int e = lane; e < d; e += 64) {
        float w = __expf(sw[e] - mx);
        sw[e] = w;
        sum += w;
      }
#pragma unroll
      for (int o = 32; o; o >>= 1) sum += __shfl_xor(sum, o);
      if (lane == 0) s_sinv[0] = 1.0f / sum;
    }
    __syncthreads();
    const float sinv = s_sinv[0];
    const int f4 = t & 15, grp = t >> 4;  // 16 outputs x 16-way edges
    float4 acc = make_float4(0.f, 0.f, 0.f, 0.f);
    for (int e = grp; e < d; e += 16) {
      const float w = sw[e];
      const float4 pv = *(const float4*)&proj1[(size_t)sm_[e] * 64 + f4 * 4];
      acc.x = fmaf(w, pv.x, acc.x);
      acc.y = fmaf(w, pv.y, acc.y);
      acc.z = fmaf(w, pv.z, acc.z);
      acc.w = fmaf(w, pv.w, acc.w);
    }
    if (grp > 0) buf[grp * 16 + f4] = acc;
    __syncthreads();
    if (grp == 0) {
#pragma unroll
      for (int p = 1; p < 16; ++p) {
        float4 v = buf[p * 16 + f4];
        acc.x += v.x; acc.y += v.y; acc.z += v.z; acc.w += v.w;
      }
      acc.x *= sinv; acc.y *= sinv; acc.z *= sinv; acc.w *= sinv;
      *(float4*)&out[(size_t)n * 64 + f4 * 4] = acc;
    }
    __syncthreads();  // smem reuse before next node
  }
}

// ---------------------------------------------------------------------------
extern "C" void kernel_launch(void* const* d_in, const int* in_sizes, int n_in,
                              void* d_out, int out_size, void* d_ws, size_t ws_size,
                              hipStream_t stream) {
  const float* x      = (const float*)d_in[0];
  const float* mask   = (const float*)d_in[1];
  const float* W0     = (const float*)d_in[2];
  const float* b0     = (const float*)d_in[3];
  const float* a_src0 = (const float*)d_in[4];
  const float* a_tgt0 = (const float*)d_in[5];
  const float* W1     = (const float*)d_in[6];
  const float* b1     = (const float*)d_in[7];
  const float* a_src1 = (const float*)d_in[8];
  const float* a_tgt1 = (const float*)d_in[9];
  float* out = (float*)d_out;

  // workspace layout (~37.3 MB of the ws)
  float* ws    = (float*)d_ws;
  float* proj0 = ws;                          // 4096*512
  float* h0    = proj0 + NNODES * 512;        // 4096*512
  float* proj1 = h0 + NNODES * 512;           // 4096*64
  float* ssrc0 = proj1 + NNODES * 64;         // 4096*8
  float* stgt0 = ssrc0 + NNODES * 8;          // 4096*8
  float* ssrc1 = stgt0 + NNODES * 8;          // 4096
  float* stgt1 = ssrc1 + NNODES;              // 4096
  int* deg  = (int*)(stgt1 + NNODES);         // 4096
  int* cols = deg + NNODES;                   // 4096*CAP
  float* part = (float*)(cols + NNODES * CAP);  // 16*4096*64 split-K partials

  int occ = 0;
  hipOccupancyMaxActiveBlocksPerMultiprocessor(&occ, (const void*)fused_gat,
                                               256, 0);
  if (occ < 1) occ = 1;
  int grid = occ * 256;  // 256 CUs
  if (grid > 2048) grid = 2048;

  void* args[] = {&mask, &x, &W0, &b0, &a_src0, &a_tgt0, &W1, &b1,
                  &a_src1, &a_tgt1, &out, &proj0, &h0, &proj1, &ssrc0,
                  &stgt0, &ssrc1, &stgt1, &deg, &cols, &part};
  hipLaunchCooperativeKernel((const void*)fused_gat, dim3(grid), dim3(256),
                             args, 0, stream);
}

// Round 12
// 79.128 us; speedup vs baseline: 7.4682x; 4.8338x over previous
//
#include <hip/hip_runtime.h>
#include <hip/hip_bf16.h>

#define NNODES 4096
#define CAP 256

// R11 lesson: grid.sync() costs ~100+ us on MI355X (2048-wg atomic rendezvous);
// dispatch boundaries are ~6 us. Multi-dispatch + data-local fusion wins.

// ---------------------------------------------------------------------------
// Phase 1 (fused): blocks [0,4096) = edge extraction rows (HBM-bound);
// blocks [4096,5120) = layer-0 GEMM tiles + fused scores0 (VALU-bound).
// ---------------------------------------------------------------------------
__global__ __launch_bounds__(256) void phase1_kernel(
    const float* __restrict__ mask, int* __restrict__ deg, int* __restrict__ cols,
    const float* __restrict__ x, const float* __restrict__ W0,
    const float* __restrict__ b0, const float* __restrict__ a_src0,
    const float* __restrict__ a_tgt0, float* __restrict__ proj0,
    float* __restrict__ ssrc0, float* __restrict__ stgt0) {
  __shared__ float smem[32 * 36 + 32 * 64];
  const int t = threadIdx.x;
  if (blockIdx.x < NNODES) {
    const int n = blockIdx.x;
    const int lane = t & 63, wid = t >> 6;
    int* wsum = (int*)smem;
    const float4* row = (const float4*)(mask + (size_t)n * NNODES);
    float4 v[4];
    int cnt = 0;
#pragma unroll
    for (int j = 0; j < 4; ++j) {
      v[j] = row[t + 256 * j];  // coalesced
      cnt += (v[j].x == 0.0f) + (v[j].y == 0.0f) + (v[j].z == 0.0f) +
             (v[j].w == 0.0f);
    }
    int xs = cnt;
#pragma unroll
    for (int o = 1; o < 64; o <<= 1) {
      int y = __shfl_up(xs, o);
      if (lane >= o) xs += y;
    }
    if (lane == 63) wsum[wid] = xs;
    __syncthreads();
    int base = 0;
    for (int w = 0; w < wid; ++w) base += wsum[w];
    int off = base + xs - cnt;
    if (t == 0) {
      int total = wsum[0] + wsum[1] + wsum[2] + wsum[3];
      deg[n] = total < CAP ? total : CAP;
    }
    int* dst = cols + (size_t)n * CAP;
#pragma unroll
    for (int j = 0; j < 4; ++j) {
      const int c0 = (t + 256 * j) * 4;
      float fv[4] = {v[j].x, v[j].y, v[j].z, v[j].w};
#pragma unroll
      for (int k = 0; k < 4; ++k) {
        if (fv[k] == 0.0f) {
          if (off < CAP) dst[off] = c0 + k;
          ++off;
        }
      }
    }
  } else {
    // gemm0: 32x64 tile, K=128, BK=32 chunks, 2x4 reg blocking + scores0
    float(*As)[36] = (float(*)[36])smem;
    float(*Ws)[64] = (float(*)[64])(smem + 32 * 36);
    const int bx = blockIdx.x - NNODES;
    const int brow = (bx & 127) * 32;
    const int head = bx >> 7;
    const int bcol = head * 64;
    const int tx = t & 15, ty = t >> 4;
    const int ar = t >> 3, ak = (t & 7) * 4;
    float acc[2][4] = {};
    for (int c = 0; c < 4; ++c) {
      const int k0 = c * 32;
      *(float4*)&As[ar][ak] =
          *(const float4*)&x[(size_t)(brow + ar) * 128 + k0 + ak];
#pragma unroll
      for (int q = 0; q < 2; ++q) {
        int i = t + q * 256;
        int k = i >> 4, c4 = (i & 15) * 4;
        *(float4*)&Ws[k][c4] =
            *(const float4*)&W0[(size_t)(k0 + k) * 512 + bcol + c4];
      }
      __syncthreads();
#pragma unroll 2
      for (int kk = 0; kk < 32; kk += 4) {
        float4 a0 = *(const float4*)&As[ty * 2 + 0][kk];
        float4 a1 = *(const float4*)&As[ty * 2 + 1][kk];
#pragma unroll
        for (int j = 0; j < 4; ++j) {
          float4 w = *(const float4*)&Ws[kk + j][tx * 4];
          float av0 = ((const float*)&a0)[j];
          float av1 = ((const float*)&a1)[j];
          acc[0][0] = fmaf(av0, w.x, acc[0][0]);
          acc[0][1] = fmaf(av0, w.y, acc[0][1]);
          acc[0][2] = fmaf(av0, w.z, acc[0][2]);
          acc[0][3] = fmaf(av0, w.w, acc[0][3]);
          acc[1][0] = fmaf(av1, w.x, acc[1][0]);
          acc[1][1] = fmaf(av1, w.y, acc[1][1]);
          acc[1][2] = fmaf(av1, w.z, acc[1][2]);
          acc[1][3] = fmaf(av1, w.w, acc[1][3]);
        }
      }
      __syncthreads();
    }
    const float4 bv = *(const float4*)&b0[bcol + tx * 4];
    const float4 as = *(const float4*)&a_src0[head * 64 + tx * 4];
    const float4 at = *(const float4*)&a_tgt0[head * 64 + tx * 4];
#pragma unroll
    for (int r = 0; r < 2; ++r) {
      float4 o;
      o.x = acc[r][0] + bv.x; o.y = acc[r][1] + bv.y;
      o.z = acc[r][2] + bv.z; o.w = acc[r][3] + bv.w;
      const size_t node = brow + ty * 2 + r;
      *(float4*)&proj0[node * 512 + bcol + tx * 4] = o;
      float ps = o.x * as.x + o.y * as.y + o.z * as.z + o.w * as.w;
      float pt = o.x * at.x + o.y * at.y + o.z * at.z + o.w * at.w;
#pragma unroll
      for (int m = 8; m; m >>= 1) {
        ps += __shfl_xor(ps, m);
        pt += __shfl_xor(pt, m);
      }
      if (tx == 0) {
        ssrc0[node * 8 + head] = ps;
        stgt0[node * 8 + head] = pt;
      }
    }
  }
}

// ---------------------------------------------------------------------------
// Fused D2, one block per node: attn layer 0 (H=8) -> h0row in LDS ->
// row-GEMM with W1 (K=512, row-local!) -> +bias -> scores1.
// Eliminates h0/part global round-trips and 2 dispatch boundaries.
// ---------------------------------------------------------------------------
__global__ __launch_bounds__(256) void attn8_gemm1_kernel(
    const float* __restrict__ proj0, const float* __restrict__ ssrc0,
    const float* __restrict__ stgt0, const int* __restrict__ deg,
    const int* __restrict__ cols, const float* __restrict__ W1,
    const float* __restrict__ b1, const float* __restrict__ a_src1,
    const float* __restrict__ a_tgt1, float* __restrict__ proj1,
    float* __restrict__ ssrc1, float* __restrict__ stgt1) {
  const int n = blockIdx.x;
  const int t = threadIdx.x;
  const int lane = t & 63, wid = t >> 6;
  __shared__ int sm_[CAP];        // 1 KB
  __shared__ float sw[CAP * 8];   // 8 KB
  __shared__ float sinv[8];
  __shared__ float h0row[512];    // 2 KB (also grp1 partial buffer)
  __shared__ float pr[4][64];     // 1 KB gemm partials
  const int d = deg[n];
  for (int i = t; i < d; i += 256) sm_[i] = cols[(size_t)n * CAP + i];
  __syncthreads();
  for (int i = t; i < d * 8; i += 256) {
    int e = i >> 3, h = i & 7;
    float s = ssrc0[n * 8 + h] + stgt0[sm_[e] * 8 + h];
    sw[i] = s >= 0.f ? s : 0.2f * s;
  }
  __syncthreads();
  for (int h = wid; h < 8; h += 4) {  // each wave owns its heads (no race)
    float mx = -1e30f;
    for (int e = lane; e < d; e += 64) mx = fmaxf(mx, sw[e * 8 + h]);
#pragma unroll
    for (int o = 32; o; o >>= 1) mx = fmaxf(mx, __shfl_xor(mx, o));
    float sum = 0.f;
    for (int e = lane; e < d; e += 64) {
      float w = __expf(sw[e * 8 + h] - mx);
      sw[e * 8 + h] = w;
      sum += w;
    }
#pragma unroll
    for (int o = 32; o; o >>= 1) sum += __shfl_xor(sum, o);
    if (lane == 0) sinv[h] = 1.0f / sum;
  }
  __syncthreads();
  // gather h0row: 128 float4 slots, 2-way edge split; grp1 stages via h0row
  const int f4 = t & 127, grp = t >> 7;
  const int hh = f4 >> 4;
  float4 acc = make_float4(0.f, 0.f, 0.f, 0.f);
  for (int e = grp; e < d; e += 2) {
    const float w = sw[e * 8 + hh];
    const float4 pv = *(const float4*)&proj0[(size_t)sm_[e] * 512 + f4 * 4];
    acc.x = fmaf(w, pv.x, acc.x);
    acc.y = fmaf(w, pv.y, acc.y);
    acc.z = fmaf(w, pv.z, acc.z);
    acc.w = fmaf(w, pv.w, acc.w);
  }
  float4* h0v = (float4*)h0row;
  if (grp == 1) h0v[f4] = acc;
  __syncthreads();
  if (grp == 0) {
    const float4 o2 = h0v[f4];
    const float s = sinv[hh];
    float4 o;
    o.x = (acc.x + o2.x) * s;
    o.y = (acc.y + o2.y) * s;
    o.z = (acc.z + o2.z) * s;
    o.w = (acc.w + o2.w) * s;
    h0v[f4] = o;
  }
  __syncthreads();
  // row-GEMM: wave w sums k in [w*128,(w+1)*128), lane = output feature.
  // W1[k][lane] reads are 256B coalesced per wave; h0row[k] is LDS broadcast.
  {
    float accum = 0.f;
    const int kbase = wid * 128;
#pragma unroll 8
    for (int k = 0; k < 128; ++k)
      accum = fmaf(h0row[kbase + k], W1[(size_t)(kbase + k) * 64 + lane], accum);
    pr[wid][lane] = accum;
  }
  __syncthreads();
  if (wid == 0) {
    float v = pr[0][lane] + pr[1][lane] + pr[2][lane] + pr[3][lane] + b1[lane];
    proj1[(size_t)n * 64 + lane] = v;
    float ps = v * a_src1[lane];
    float pt = v * a_tgt1[lane];
#pragma unroll
    for (int o = 32; o; o >>= 1) {
      ps += __shfl_xor(ps, o);
      pt += __shfl_xor(pt, o);
    }
    if (lane == 0) {
      ssrc1[n] = ps;
      stgt1[n] = pt;
    }
  }
}

// ---------------------------------------------------------------------------
// Sparse attention, H=1: one wave per node; float4 gather, 4-way edge split.
// ---------------------------------------------------------------------------
__global__ void attn1_kernel(
    const float* __restrict__ proj, const float* __restrict__ s_src,
    const float* __restrict__ s_tgt, const int* __restrict__ deg,
    const int* __restrict__ cols, float* __restrict__ out) {
  const int n = blockIdx.x;
  const int tid = threadIdx.x;  // 64 threads = 1 wave
  __shared__ int sm_[CAP];
  __shared__ float sw[CAP];
  const int d = deg[n];
  for (int i = tid; i < d; i += 64) sm_[i] = cols[(size_t)n * CAP + i];
  __syncthreads();
  const float ssn = s_src[n];
  for (int i = tid; i < d; i += 64) {
    float s = ssn + s_tgt[sm_[i]];
    sw[i] = s >= 0.f ? s : 0.2f * s;
  }
  __syncthreads();
  float mx = -1e30f;
  for (int e = tid; e < d; e += 64) mx = fmaxf(mx, sw[e]);
#pragma unroll
  for (int o = 32; o; o >>= 1) mx = fmaxf(mx, __shfl_xor(mx, o));
  float sum = 0.f;
  for (int e = tid; e < d; e += 64) {
    float w = __expf(sw[e] - mx);
    sw[e] = w;
    sum += w;
  }
#pragma unroll
  for (int o = 32; o; o >>= 1) sum += __shfl_xor(sum, o);
  const float sinv = 1.0f / sum;
  __syncthreads();
  const int f4 = tid & 15, grp = tid >> 4;  // 16 float4 outputs, 4-way edges
  float4 acc = make_float4(0.f, 0.f, 0.f, 0.f);
  for (int e = grp; e < d; e += 4) {
    const float w = sw[e];
    const float4 pv = *(const float4*)&proj[(size_t)sm_[e] * 64 + f4 * 4];
    acc.x = fmaf(w, pv.x, acc.x);
    acc.y = fmaf(w, pv.y, acc.y);
    acc.z = fmaf(w, pv.z, acc.z);
    acc.w = fmaf(w, pv.w, acc.w);
  }
#pragma unroll
  for (int o = 16; o <= 32; o <<= 1) {
    acc.x += __shfl_xor(acc.x, o);
    acc.y += __shfl_xor(acc.y, o);
    acc.z += __shfl_xor(acc.z, o);
    acc.w += __shfl_xor(acc.w, o);
  }
  if (grp == 0) {
    acc.x *= sinv; acc.y *= sinv; acc.z *= sinv; acc.w *= sinv;
    *(float4*)&out[(size_t)n * 64 + f4 * 4] = acc;
  }
}

// ---------------------------------------------------------------------------
extern "C" void kernel_launch(void* const* d_in, const int* in_sizes, int n_in,
                              void* d_out, int out_size, void* d_ws, size_t ws_size,
                              hipStream_t stream) {
  const float* x      = (const float*)d_in[0];
  const float* mask   = (const float*)d_in[1];
  const float* W0     = (const float*)d_in[2];
  const float* b0     = (const float*)d_in[3];
  const float* a_src0 = (const float*)d_in[4];
  const float* a_tgt0 = (const float*)d_in[5];
  const float* W1     = (const float*)d_in[6];
  const float* b1     = (const float*)d_in[7];
  const float* a_src1 = (const float*)d_in[8];
  const float* a_tgt1 = (const float*)d_in[9];
  float* out = (float*)d_out;

  // workspace layout (~13.4 MB)
  float* ws    = (float*)d_ws;
  float* proj0 = ws;                          // 4096*512
  float* proj1 = proj0 + NNODES * 512;        // 4096*64
  float* ssrc0 = proj1 + NNODES * 64;         // 4096*8
  float* stgt0 = ssrc0 + NNODES * 8;          // 4096*8
  float* ssrc1 = stgt0 + NNODES * 8;          // 4096
  float* stgt1 = ssrc1 + NNODES;              // 4096
  int* deg  = (int*)(stgt1 + NNODES);         // 4096
  int* cols = deg + NNODES;                   // 4096*CAP

  // D1: edge extraction (4096 blocks) overlapped with gemm0+scores0 (1024)
  phase1_kernel<<<NNODES + 1024, 256, 0, stream>>>(
      mask, deg, cols, x, W0, b0, a_src0, a_tgt0, proj0, ssrc0, stgt0);
  // D2: attn0 + row-local gemm1 + bias + scores1, one block per node
  attn8_gemm1_kernel<<<NNODES, 256, 0, stream>>>(
      proj0, ssrc0, stgt0, deg, cols, W1, b1, a_src1, a_tgt1,
      proj1, ssrc1, stgt1);
  // D3: attn layer 1
  attn1_kernel<<<NNODES, 64, 0, stream>>>(proj1, ssrc1, stgt1, deg, cols, out);
}